// Round 2
// baseline (604.870 us; speedup 1.0000x reference)
//
#include <hip/hip_runtime.h>
#include <hip/hip_bf16.h>

#define N_TOK 2048
#define B_SZ  8
#define E_DIM 256
#define H_DIM 512
#define SPLIT 2
#define KEYS_PER_BLOCK (N_TOK / SPLIT)   // 1024
#define ITERS (KEYS_PER_BLOCK / 32)      // 32

typedef __attribute__((ext_vector_type(8))) short bf16x8;
typedef __attribute__((ext_vector_type(4))) float f32x4;

__device__ __forceinline__ unsigned short f2bf(float f) {
    union { float f; unsigned u; } v; v.f = f;
    unsigned r = v.u + 0x7FFF + ((v.u >> 16) & 1);   // RNE
    return (unsigned short)(r >> 16);
}
__device__ __forceinline__ float bf2f(unsigned short b) {
    union { unsigned u; float f; } v; v.u = ((unsigned)b) << 16;
    return v.f;
}

// ---------------- Kernel 1: row-normalize x -> Xn bf16, layout (B, N, E) ----
__global__ void norm_kernel(const float* __restrict__ x,
                            unsigned short* __restrict__ Xn) {
    int r = blockIdx.x;            // r = i*B + b  (memory order of x)
    int i = r >> 3, b = r & 7;     // B_SZ == 8
    int t = threadIdx.x;           // 256 threads == E_DIM
    float v = x[(size_t)r * E_DIM + t];
    float s = v * v;
    #pragma unroll
    for (int o = 32; o > 0; o >>= 1) s += __shfl_xor(s, o);
    __shared__ float red[4];
    int lane = t & 63, w = t >> 6;
    if (lane == 0) red[w] = s;
    __syncthreads();
    float tot = red[0] + red[1] + red[2] + red[3];
    float rn = 1.0f / sqrtf(tot);
    Xn[((size_t)b * N_TOK + i) * E_DIM + t] = f2bf(v * rn);
}

// ---------------- Kernel 2: transpose h (N,B,H) f32 -> Vt (B,H,N) bf16 -----
__global__ void transpose_kernel(const float* __restrict__ h,
                                 unsigned short* __restrict__ Vt) {
    __shared__ float tile[32][33];
    int j0 = blockIdx.x * 32, h0 = blockIdx.y * 32, b = blockIdx.z;
    int tx = threadIdx.x & 31, ty = threadIdx.x >> 5;   // 32 x 8 threads
    #pragma unroll
    for (int it = 0; it < 4; it++) {
        int j = j0 + ty + it * 8;
        tile[ty + it * 8][tx] = h[((size_t)j * B_SZ + b) * H_DIM + h0 + tx];
    }
    __syncthreads();
    #pragma unroll
    for (int it = 0; it < 4; it++) {
        int hh = h0 + ty + it * 8;
        Vt[((size_t)b * H_DIM + hh) * N_TOK + j0 + tx] = f2bf(tile[tx][ty + it * 8]);
    }
}

// ---------------- Kernel 3: flash attention, split-K, 1 barrier/iter --------
// grid (N/32, B, SPLIT), 256 threads (4 waves).
// Wave w: rg = w>>1 (16 q-rows), hh = w&1 (256 H-cols). QK redundancy x2.
// K tile (32 keys x 256 dims bf16) staged via global_load_lds, double-buffered,
// XOR-swizzled in 16B units so ds_read_b128 is conflict-free.
#define PT_STRIDE 40   // shorts; 80B: 16B-aligned, 2-way (free) on b128 reads

__launch_bounds__(256, 3)
__global__ void flash_kernel(const unsigned short* __restrict__ Xn,
                             const unsigned short* __restrict__ Vt,
                             float* __restrict__ part0,   // == out (N,B,H)
                             float* __restrict__ part1,   // ws partial
                             float* __restrict__ mlbuf) { // [split][{m,l}][B][N]
    __shared__ __attribute__((aligned(16))) unsigned short Kbuf[2][32 * 256];
    __shared__ __attribute__((aligned(16))) unsigned short Pt[4][16 * PT_STRIDE];

    int q0 = blockIdx.x * 32;
    int b  = blockIdx.y;
    int kb = blockIdx.z;
    int t = threadIdx.x;
    int w = t >> 6, lane = t & 63;
    int quad = lane >> 4, nm = lane & 15;
    int rg = w >> 1, hh = w & 1;

    const unsigned short* Kbase =
        Xn + ((size_t)b * N_TOK + (size_t)kb * KEYS_PER_BLOCK) * E_DIM;
    const unsigned short* Qrow =
        Xn + ((size_t)b * N_TOK + q0 + rg * 16 + nm) * E_DIM;
    const unsigned short* Vbase =
        Vt + ((size_t)b * H_DIM + hh * 256) * N_TOK + (size_t)kb * KEYS_PER_BLOCK;

    // Q fragments, register-resident (32 VGPR)
    bf16x8 qf[8];
    #pragma unroll
    for (int ec = 0; ec < 8; ec++)
        qf[ec] = *(const bf16x8*)(Qrow + ec * 32 + quad * 8);

    f32x4 O[16];
    #pragma unroll
    for (int i = 0; i < 16; i++) O[i] = (f32x4){0.f, 0.f, 0.f, 0.f};
    float m_cur[4], l_cur[4];
    #pragma unroll
    for (int r = 0; r < 4; r++) { m_cur[r] = -INFINITY; l_cur[r] = 0.0f; }

    // staging lambda: wave w stages rows [w*8, w*8+8) of the 32x256 tile
    // LDS unit i (16B) of row holds global 16B-chunk (i ^ (row&7))
    auto stage = [&](int tile, int buf) {
        int j0 = tile * 32;
        #pragma unroll
        for (int k = 0; k < 4; k++) {
            int unit = w * 256 + k * 64 + lane;      // 0..1023
            int row  = unit >> 5;
            int u    = unit & 31;
            const unsigned short* src =
                Kbase + (size_t)(j0 + row) * E_DIM + ((u ^ (row & 7)) * 8);
            __builtin_amdgcn_global_load_lds(
                (const __attribute__((address_space(1))) unsigned int*)src,
                (__attribute__((address_space(3))) unsigned int*)
                    (&Kbuf[buf][(w * 256 + k * 64) * 8]),
                16, 0, 0);
        }
    };

    stage(0, 0);

    for (int it = 0; it < ITERS; ++it) {
        __syncthreads();                 // drains staging of tile `it`
        int cur = it & 1;
        if (it + 1 < ITERS) stage(it + 1, cur ^ 1);
        const unsigned short* KB = &Kbuf[cur][0];

        // ---- QK^T: 16 q-rows x 32 keys (2 col-tiles), K=256 ----
        f32x4 s0 = (f32x4){0.f,0.f,0.f,0.f}, s1 = (f32x4){0.f,0.f,0.f,0.f};
        #pragma unroll
        for (int ec = 0; ec < 8; ec++) {
            int r0 = nm,      u0 = (ec * 4 + quad) ^ (r0 & 7);
            int r1 = 16 + nm, u1 = (ec * 4 + quad) ^ (r1 & 7);
            bf16x8 kf0 = *(const bf16x8*)(KB + r0 * 256 + u0 * 8);
            bf16x8 kf1 = *(const bf16x8*)(KB + r1 * 256 + u1 * 8);
            s0 = __builtin_amdgcn_mfma_f32_16x16x32_bf16(qf[ec], kf0, s0, 0, 0, 0);
            s1 = __builtin_amdgcn_mfma_f32_16x16x32_bf16(qf[ec], kf1, s1, 0, 0, 0);
        }

        // ---- wave-local online softmax (rows quad*4+r, reduce over 16 nm) --
        float alpha[4];
        #pragma unroll
        for (int r = 0; r < 4; r++) {
            float v = fmaxf(s0[r], s1[r]);
            #pragma unroll
            for (int o = 1; o < 16; o <<= 1) v = fmaxf(v, __shfl_xor(v, o));
            float mn = fmaxf(m_cur[r], v);
            alpha[r] = __expf(m_cur[r] - mn);
            m_cur[r] = mn;
            unsigned short pb0 = f2bf(__expf(s0[r] - mn));
            unsigned short pb1 = f2bf(__expf(s1[r] - mn));
            float ps = bf2f(pb0) + bf2f(pb1);
            #pragma unroll
            for (int o = 1; o < 16; o <<= 1) ps += __shfl_xor(ps, o);
            l_cur[r] = l_cur[r] * alpha[r] + ps;
            Pt[w][(quad * 4 + r) * PT_STRIDE + nm]      = pb0;
            Pt[w][(quad * 4 + r) * PT_STRIDE + 16 + nm] = pb1;
        }
        asm volatile("s_waitcnt lgkmcnt(0)" ::: "memory");
        __builtin_amdgcn_wave_barrier();
        bf16x8 pf = *(const bf16x8*)(&Pt[w][nm * PT_STRIDE + quad * 8]);

        // ---- rescale O, then PV (16 col-tiles x K=32) ----
        #pragma unroll
        for (int tile = 0; tile < 16; tile++)
            #pragma unroll
            for (int r = 0; r < 4; r++)
                O[tile][r] *= alpha[r];
        #pragma unroll
        for (int tile = 0; tile < 16; tile++) {
            bf16x8 vf = *(const bf16x8*)
                (Vbase + (size_t)(tile * 16 + nm) * N_TOK + it * 32 + quad * 8);
            O[tile] = __builtin_amdgcn_mfma_f32_16x16x32_bf16(pf, vf, O[tile], 0, 0, 0);
        }
    }

    // ---- epilogue: write unnormalized partial O + (m,l) ----
    float* dst = (kb == 0) ? part0 : part1;
    #pragma unroll
    for (int tile = 0; tile < 16; tile++) {
        #pragma unroll
        for (int r = 0; r < 4; r++) {
            int grow = q0 + rg * 16 + quad * 4 + r;
            int col  = hh * 256 + tile * 16 + nm;
            dst[((size_t)grow * B_SZ + b) * H_DIM + col] = O[tile][r];
        }
    }
    if (nm == 0 && hh == 0) {
        #pragma unroll
        for (int r = 0; r < 4; r++) {
            int grow = q0 + rg * 16 + quad * 4 + r;
            mlbuf[((size_t)(kb * 2 + 0) * B_SZ + b) * N_TOK + grow] = m_cur[r];
            mlbuf[((size_t)(kb * 2 + 1) * B_SZ + b) * N_TOK + grow] = l_cur[r];
        }
    }
}

// ---------------- Kernel 4: combine split-K partials + sumsq ----------------
__global__ void combine_kernel(float* __restrict__ out,        // partial 0 -> final
                               const float* __restrict__ part1,
                               const float* __restrict__ mlbuf,
                               float* __restrict__ sumsq) {
    int t = threadIdx.x;
    int rI = blockIdx.x * 2 + (t >> 7);      // row index in (N*B)
    int c4 = (t & 127) * 4;
    int n = rI >> 3, b = rI & 7;
    float m1 = mlbuf[((size_t)(0 * 2 + 0) * B_SZ + b) * N_TOK + n];
    float l1 = mlbuf[((size_t)(0 * 2 + 1) * B_SZ + b) * N_TOK + n];
    float m2 = mlbuf[((size_t)(1 * 2 + 0) * B_SZ + b) * N_TOK + n];
    float l2 = mlbuf[((size_t)(1 * 2 + 1) * B_SZ + b) * N_TOK + n];
    float M  = fmaxf(m1, m2);
    float w1 = __expf(m1 - M), w2 = __expf(m2 - M);
    float inv = 1.0f / (l1 * w1 + l2 * w2);
    float a1 = w1 * inv, a2 = w2 * inv;
    size_t idx = (size_t)rI * H_DIM + c4;
    float4 o1 = *(const float4*)(out + idx);
    float4 o2 = *(const float4*)(part1 + idx);
    float4 v;
    v.x = o1.x * a1 + o2.x * a2;
    v.y = o1.y * a1 + o2.y * a2;
    v.z = o1.z * a1 + o2.z * a2;
    v.w = o1.w * a1 + o2.w * a2;
    *(float4*)(out + idx) = v;
    float ss = v.x * v.x + v.y * v.y + v.z * v.z + v.w * v.w;
    #pragma unroll
    for (int o = 1; o < 64; o <<= 1) ss += __shfl_xor(ss, o);
    __shared__ float red[4];
    int lane = t & 63, w = t >> 6;
    if (lane == 0) red[w] = ss;
    __syncthreads();
    if (t == 0) atomicAdd(sumsq, red[0] + red[1] + red[2] + red[3]);
}

// ---------------- Kernel 5: global-norm rescale -----------------------------
__global__ void scale_kernel(float* __restrict__ out,
                             const float* __restrict__ sumsq) {
    size_t idx = ((size_t)blockIdx.x * blockDim.x + threadIdx.x) * 4;
    float rs = 1.0f / sqrtf(*sumsq);
    float4 v = *(float4*)(out + idx);
    v.x *= rs; v.y *= rs; v.z *= rs; v.w *= rs;
    *(float4*)(out + idx) = v;
}

extern "C" void kernel_launch(void* const* d_in, const int* in_sizes, int n_in,
                              void* d_out, int out_size, void* d_ws, size_t ws_size,
                              hipStream_t stream) {
    const float* x = (const float*)d_in[0];
    const float* h = (const float*)d_in[1];
    float* out = (float*)d_out;

    unsigned short* Xn = (unsigned short*)d_ws;                  // 8.4 MB
    unsigned short* Vt = Xn + (size_t)B_SZ * N_TOK * E_DIM;      // 16.8 MB
    float* part1 = (float*)(Vt + (size_t)B_SZ * H_DIM * N_TOK);  // 33.6 MB
    float* mlbuf = part1 + (size_t)N_TOK * B_SZ * H_DIM;         // 256 KB
    float* sumsq = mlbuf + (size_t)SPLIT * 2 * B_SZ * N_TOK;     // 4 B

    hipMemsetAsync(sumsq, 0, sizeof(float), stream);
    norm_kernel<<<N_TOK * B_SZ, 256, 0, stream>>>(x, Xn);
    transpose_kernel<<<dim3(N_TOK / 32, H_DIM / 32, B_SZ), 256, 0, stream>>>(h, Vt);
    flash_kernel<<<dim3(N_TOK / 32, B_SZ, SPLIT), 256, 0, stream>>>(Xn, Vt, out, part1, mlbuf);
    combine_kernel<<<(N_TOK * B_SZ) / 2, 256, 0, stream>>>(out, part1, mlbuf, sumsq);
    scale_kernel<<<out_size / (4 * 256), 256, 0, stream>>>(out, sumsq);
}

// Round 3
// 271.101 us; speedup vs baseline: 2.2312x; 2.2312x over previous
//
#include <hip/hip_runtime.h>
#include <hip/hip_bf16.h>

#define N_TOK 2048
#define B_SZ  8
#define E_DIM 256
#define H_DIM 512
#define ITERS (N_TOK / 32)     // 64

typedef __attribute__((ext_vector_type(8))) short bf16x8;
typedef __attribute__((ext_vector_type(4))) float f32x4;

__device__ __forceinline__ unsigned short f2bf(float f) {
    union { float f; unsigned u; } v; v.f = f;
    unsigned r = v.u + 0x7FFF + ((v.u >> 16) & 1);   // RNE
    return (unsigned short)(r >> 16);
}
__device__ __forceinline__ float bf2f(unsigned short b) {
    union { unsigned u; float f; } v; v.u = ((unsigned)b) << 16;
    return v.f;
}

// ---- Kernel 1: row-normalize x -> Xn bf16 (B,N,E), 16B units XOR-swizzled --
// unit u of row r stored at position u ^ (r & 7)  (u = e/8, 32 units/row)
__global__ void norm_kernel(const float* __restrict__ x,
                            unsigned short* __restrict__ Xn) {
    int r = blockIdx.x;            // r = i*B + b  (memory order of x)
    int i = r >> 3, b = r & 7;
    int t = threadIdx.x;           // 256 threads == E_DIM
    float v = x[(size_t)r * E_DIM + t];
    float s = v * v;
    #pragma unroll
    for (int o = 32; o > 0; o >>= 1) s += __shfl_xor(s, o);
    __shared__ float red[4];
    int lane = t & 63, w = t >> 6;
    if (lane == 0) red[w] = s;
    __syncthreads();
    float tot = red[0] + red[1] + red[2] + red[3];
    float rn = 1.0f / sqrtf(tot);
    int u = t >> 3, lo = t & 7;
    Xn[((size_t)b * N_TOK + i) * E_DIM + (size_t)((u ^ (i & 7)) * 8 + lo)] =
        f2bf(v * rn);
}

// ---- Kernel 2: pack h (N,B,H) f32 -> Vp (B, N/32, H, 32) bf16, swizzled ----
// Within a 32-key tile: 16B unit (h, jg) (jg=j'/8) stored at h*4 + (jg ^ ((h>>1)&3)).
__global__ void pack_v(const float* __restrict__ h,
                       unsigned short* __restrict__ Vp) {
    __shared__ float tile[32][33];
    int j0 = blockIdx.x * 32, h0 = blockIdx.y * 32, b = blockIdx.z;
    int tx = threadIdx.x & 31, ty = threadIdx.x >> 5;   // 32 x 8
    #pragma unroll
    for (int it = 0; it < 4; it++) {
        int j = j0 + ty + it * 8;
        tile[ty + it * 8][tx] = h[((size_t)j * B_SZ + b) * H_DIM + h0 + tx];
    }
    __syncthreads();
    size_t base = ((size_t)b * (N_TOK / 32) + blockIdx.x) * (H_DIM * 32);
    #pragma unroll
    for (int it = 0; it < 4; it++) {
        int hc = h0 + ty + it * 8;           // h column
        int jg = tx >> 3, swz = (hc >> 1) & 3;
        Vp[base + (size_t)(hc * 4 + (jg ^ swz)) * 8 + (tx & 7)] =
            f2bf(tile[tx][ty + it * 8]);
    }
}

// ---- Kernel 3: fused flash attention -------------------------------------
// grid (N/32, B), 256 threads (4 waves). Wave w: rg=w>>1 (16 q-rows, QK dup x2),
// hh=w&1 (256 h-cols). K dbl-buffered LDS (sequential global_load_lds, swizzle
// pre-baked in Xn). V fragments read directly from packed Vp: 1KB contiguous
// per instruction, issued at iter top (L2 latency hidden by QK+softmax).
#define PT_STRIDE 40   // shorts

__launch_bounds__(256, 2)
__global__ void flash_kernel(const unsigned short* __restrict__ Xn,
                             const unsigned short* __restrict__ Vp,
                             float* __restrict__ out,
                             float* __restrict__ sumsq) {
    __shared__ __attribute__((aligned(16))) unsigned short Kbuf[2][32 * 256];
    __shared__ __attribute__((aligned(16))) unsigned short Pt[4][16 * PT_STRIDE];

    int q0 = blockIdx.x * 32;
    int b  = blockIdx.y;
    int t = threadIdx.x;
    int w = t >> 6, lane = t & 63;
    int quad = lane >> 4, nm = lane & 15;
    int rg = w >> 1, hh = w & 1;

    const unsigned short* Kbase = Xn + (size_t)b * N_TOK * E_DIM;
    const unsigned short* Qrow =
        Xn + ((size_t)b * N_TOK + q0 + rg * 16 + nm) * E_DIM;
    const unsigned short* Vtile0 = Vp + (size_t)b * (N_TOK / 32) * (H_DIM * 32);

    // Q fragments (swizzled layout: unit (ec*4+quad) ^ (row&7))
    bf16x8 qf[8];
    #pragma unroll
    for (int ec = 0; ec < 8; ec++)
        qf[ec] = *(const bf16x8*)(Qrow + (size_t)(((ec * 4 + quad) ^ (nm & 7)) * 8));

    f32x4 O[16];
    #pragma unroll
    for (int i = 0; i < 16; i++) O[i] = (f32x4){0.f, 0.f, 0.f, 0.f};
    float m_cur[4], l_cur[4];
    #pragma unroll
    for (int r = 0; r < 4; r++) { m_cur[r] = -INFINITY; l_cur[r] = 0.0f; }

    // K staging: straight sequential copy of the 16KB tile (swizzle pre-baked)
    auto stage = [&](int tile, int buf) {
        const unsigned short* src0 = Kbase + (size_t)tile * 32 * E_DIM;
        #pragma unroll
        for (int k = 0; k < 4; k++) {
            int chunk = w * 4 + k;                 // 0..15, 1KB each
            __builtin_amdgcn_global_load_lds(
                (const __attribute__((address_space(1))) unsigned int*)
                    (src0 + (size_t)chunk * 512 + lane * 8),
                (__attribute__((address_space(3))) unsigned int*)
                    (&Kbuf[buf][chunk * 512]),
                16, 0, 0);
        }
    };

    stage(0, 0);
    int vswz = (quad ^ ((nm >> 1) & 3)) * 8;

    for (int it = 0; it < ITERS; ++it) {
        __syncthreads();                 // drains staging of tile `it`
        int cur = it & 1;

        // ---- V fragment prefetch (this iter), contiguous 1KB per instr ----
        const unsigned short* Vt = Vtile0 + (size_t)it * (H_DIM * 32);
        bf16x8 vf[16];
        #pragma unroll
        for (int tt = 0; tt < 16; tt++) {
            int hc = hh * 256 + tt * 16 + nm;
            vf[tt] = *(const bf16x8*)(Vt + (size_t)(hc * 4) * 8 + vswz);
        }

        if (it + 1 < ITERS) stage(it + 1, cur ^ 1);
        const unsigned short* KB = &Kbuf[cur][0];

        // ---- QK^T: 16 q-rows x 32 keys, K=256 ----
        f32x4 s0 = (f32x4){0.f,0.f,0.f,0.f}, s1 = (f32x4){0.f,0.f,0.f,0.f};
        #pragma unroll
        for (int ec = 0; ec < 8; ec++) {
            int u = ((ec * 4 + quad) ^ (nm & 7)) * 8;
            bf16x8 kf0 = *(const bf16x8*)(KB + nm * 256 + u);
            bf16x8 kf1 = *(const bf16x8*)(KB + (16 + nm) * 256 + u);
            s0 = __builtin_amdgcn_mfma_f32_16x16x32_bf16(qf[ec], kf0, s0, 0, 0, 0);
            s1 = __builtin_amdgcn_mfma_f32_16x16x32_bf16(qf[ec], kf1, s1, 0, 0, 0);
        }

        // ---- wave-local online softmax (rows quad*4+r, reduce over 16 nm) --
        float alpha[4];
        #pragma unroll
        for (int r = 0; r < 4; r++) {
            float v = fmaxf(s0[r], s1[r]);
            #pragma unroll
            for (int o = 1; o < 16; o <<= 1) v = fmaxf(v, __shfl_xor(v, o));
            float mn = fmaxf(m_cur[r], v);
            alpha[r] = __expf(m_cur[r] - mn);
            m_cur[r] = mn;
            unsigned short pb0 = f2bf(__expf(s0[r] - mn));
            unsigned short pb1 = f2bf(__expf(s1[r] - mn));
            float ps = bf2f(pb0) + bf2f(pb1);
            #pragma unroll
            for (int o = 1; o < 16; o <<= 1) ps += __shfl_xor(ps, o);
            l_cur[r] = l_cur[r] * alpha[r] + ps;
            Pt[w][(quad * 4 + r) * PT_STRIDE + nm]      = pb0;
            Pt[w][(quad * 4 + r) * PT_STRIDE + 16 + nm] = pb1;
        }
        asm volatile("s_waitcnt lgkmcnt(0)" ::: "memory");
        __builtin_amdgcn_wave_barrier();
        bf16x8 pf = *(const bf16x8*)(&Pt[w][nm * PT_STRIDE + quad * 8]);

        // ---- rescale O, then PV (16 col-tiles x K=32) ----
        #pragma unroll
        for (int tt = 0; tt < 16; tt++)
            #pragma unroll
            for (int r = 0; r < 4; r++)
                O[tt][r] *= alpha[r];
        #pragma unroll
        for (int tt = 0; tt < 16; tt++)
            O[tt] = __builtin_amdgcn_mfma_f32_16x16x32_bf16(pf, vf[tt], O[tt], 0, 0, 0);
    }

    // ---- epilogue: divide by l, write g, accumulate sum of squares ----
    float linv[4];
    #pragma unroll
    for (int r = 0; r < 4; r++) linv[r] = 1.0f / l_cur[r];

    float ss = 0.0f;
    #pragma unroll
    for (int tt = 0; tt < 16; tt++) {
        #pragma unroll
        for (int r = 0; r < 4; r++) {
            float val = O[tt][r] * linv[r];
            int row = q0 + rg * 16 + quad * 4 + r;
            int col = hh * 256 + tt * 16 + nm;
            out[((size_t)row * B_SZ + b) * H_DIM + col] = val;
            ss += val * val;
        }
    }
    #pragma unroll
    for (int o = 1; o < 64; o <<= 1) ss += __shfl_xor(ss, o);
    if (lane == 0) atomicAdd(sumsq, ss);
}

// ---- Kernel 4: global-norm rescale ----------------------------------------
__global__ void scale_kernel(float* __restrict__ out,
                             const float* __restrict__ sumsq) {
    size_t idx = ((size_t)blockIdx.x * blockDim.x + threadIdx.x) * 4;
    float rs = 1.0f / sqrtf(*sumsq);
    float4 v = *(float4*)(out + idx);
    v.x *= rs; v.y *= rs; v.z *= rs; v.w *= rs;
    *(float4*)(out + idx) = v;
}

extern "C" void kernel_launch(void* const* d_in, const int* in_sizes, int n_in,
                              void* d_out, int out_size, void* d_ws, size_t ws_size,
                              hipStream_t stream) {
    const float* x = (const float*)d_in[0];
    const float* h = (const float*)d_in[1];
    float* out = (float*)d_out;

    unsigned short* Xn = (unsigned short*)d_ws;                  // 8.4 MB
    unsigned short* Vp = Xn + (size_t)B_SZ * N_TOK * E_DIM;      // 16.8 MB
    float* sumsq = (float*)(Vp + (size_t)B_SZ * N_TOK * H_DIM); // 4 B

    hipMemsetAsync(sumsq, 0, sizeof(float), stream);
    norm_kernel<<<N_TOK * B_SZ, 256, 0, stream>>>(x, Xn);
    pack_v<<<dim3(N_TOK / 32, H_DIM / 32, B_SZ), 256, 0, stream>>>(h, Vp);
    flash_kernel<<<dim3(N_TOK / 32, B_SZ), 256, 0, stream>>>(Xn, Vp, out, sumsq);
    scale_kernel<<<out_size / (4 * 256), 256, 0, stream>>>(out, sumsq);
}